// Round 6
// baseline (4940.363 us; speedup 1.0000x reference)
//
#include <hip/hip_runtime.h>

#define HID  256
#define DDYN 5
#define NS   27
#define TS   365
#define BS   4            // batch rows per block
#define NW   16           // waves per block
#define UPW  16           // hidden units owned per wave
#define NTILE 3           // 16-col MFMA tiles per wave
#define SA   264          // Abuf row stride in bf16 elems (256 h + 8 pad)
#define G3   768          // 3 gates * 256

typedef short short8 __attribute__((ext_vector_type(8)));
typedef float f32x4  __attribute__((ext_vector_type(4)));

__device__ __forceinline__ unsigned short f2bf(float f) {
    union { float f; unsigned u; } v; v.f = f;
    unsigned r = v.u + 0x7FFFu + ((v.u >> 16) & 1u);   // RNE
    return (unsigned short)(r >> 16);
}
__device__ __forceinline__ float bf2f(unsigned short s) {
    union { unsigned u; float f; } v; v.u = ((unsigned)s) << 16;
    return v.f;
}
__device__ __forceinline__ float bf2f_s(short s) {
    union { unsigned u; float f; } v; v.u = ((unsigned)(unsigned short)s) << 16;
    return v.f;
}
__device__ __forceinline__ float fsig(float x) {
    float e = __builtin_amdgcn_exp2f(-1.4426950408889634f * x);
    return __builtin_amdgcn_rcpf(1.0f + e);
}
__device__ __forceinline__ float ftanh(float x) {
    float e = __builtin_amdgcn_exp2f(2.8853900817779268f * x);
    return 1.0f - 2.0f * __builtin_amdgcn_rcpf(1.0f + e);
}

// R5 post-mortem: loop-live demand must sit BELOW the 128 (V+A)/wave cap at
// 1024 threads. The x/bias MFMA (chunk 8) cost ~14 transient regs (b8 frag,
// conditional A frag, exec juggling, addresses) and pushed us over -> 202 MB
// of per-step scratch traffic = the entire runtime. It is a rank-6 update:
// do it with ~20 scalar FMAs in phase B from LDS instead. Loop-live now:
// Bf 96 + acc 12 (AGPR) + A-frag pipeline ~8 + state ~6 <= cap.
__global__ __launch_bounds__(1024)
void ealstm_kernel(const float* __restrict__ x_dyn,  const float* __restrict__ x_stat,
                   const float* __restrict__ W_i,    const float* __restrict__ b_i,
                   const float* __restrict__ W_f,    const float* __restrict__ b_f,
                   const float* __restrict__ W_g,    const float* __restrict__ b_g,
                   const float* __restrict__ W_o,    const float* __restrict__ b_o,
                   const float* __restrict__ W_head, const float* __restrict__ b_head,
                   float* __restrict__ out)
{
    // LDS: 16896 + 12288 + 12288 + 23360 + 432 = 65264 B (<= 64 KiB)
    __shared__ __align__(16) unsigned short Abuf[2][16 * SA]; // h-only A tile, double-buffered
    __shared__ __align__(16) float          pre[NW * 192];    // h-part preacts, wave-private
    __shared__ __align__(16) unsigned short WxL[G3 * 8];      // per col: Wx[0..4], bias, 0, 0 (bf16)
    __shared__ __align__(16) unsigned short xcA[TS * 4 * 8];  // per (t,row): x[0..4], 1.0, 0, 0 (bf16)
    __shared__ __align__(16) float          xst[BS * NS];

    const int tid  = threadIdx.x;
    const int bid  = blockIdx.x;
    const int b0   = bid * BS;
    const int lane = tid & 63;
    const int wv   = tid >> 6;        // wave 0..15
    const int q    = lane >> 4;       // quad 0..3 (MFMA K-group)
    const int n    = lane & 15;       // MFMA col-in-tile
    const int up   = lane >> 2;       // unit-local 0..15 (phase B)
    const int r    = lane & 3;        // batch row 0..3 (phase B)
    const int u    = wv * UPW + up;   // owned hidden unit (phase B)

    // ---- init LDS ----
    for (int i = tid; i < 2 * 16 * SA / 2; i += 1024)
        ((unsigned int*)Abuf)[i] = 0u;                 // zero both A buffers (h0 = 0)
    for (int i = tid; i < BS * NS; i += 1024)
        xst[i] = x_stat[(b0 + i / NS) * NS + (i % NS)];
    for (int i = tid; i < TS * BS; i += 1024) {        // x rows, 16B-aligned per (t,row)
        int t = i >> 2, rr = i & 3;
        const float* xp = x_dyn + ((size_t)(b0 + rr) * TS + t) * DDYN;
        unsigned short* dst = &xcA[(unsigned)i * 8];
        #pragma unroll
        for (int d = 0; d < DDYN; d++) dst[d] = f2bf(xp[d]);
        dst[5] = 0x3F80; dst[6] = 0; dst[7] = 0;
    }
    if (tid < G3) {
        int col = tid;
        int gate = col >> 8, hc = col & 255;
        const float* Wg = gate == 0 ? W_f : (gate == 1 ? W_g : W_o);
        const float* bg = gate == 0 ? b_f : (gate == 1 ? b_g : b_o);
        #pragma unroll
        for (int d = 0; d < DDYN; d++) WxL[col * 8 + d] = f2bf(Wg[hc * (DDYN + HID) + d]);
        WxL[col * 8 + 5] = f2bf(bg[hc]);
        WxL[col * 8 + 6] = 0; WxL[col * 8 + 7] = 0;
    }

    // ---- persistent B fragments: 3 tiles x 8 K-chunks x 4 VGPR = 96 regs ----
    short8 Bf[NTILE][8];
    #pragma unroll
    for (int j = 0; j < NTILE; j++) {
        int urow = wv * UPW + n;           // weight row (hidden unit), gate j
        const float* Wg = j == 0 ? W_f : (j == 1 ? W_g : W_o);
        const float* wrow = Wg + urow * (DDYN + HID) + DDYN;   // skip x-part
        #pragma unroll
        for (int c = 0; c < 8; c++) {
            int k0 = c * 32 + q * 8;
            short8 fr;
            #pragma unroll
            for (int e = 0; e < 8; e++) fr[e] = (short)f2bf(wrow[k0 + e]);
            Bf[j][c] = fr;
        }
    }
    __syncthreads();

    // ---- i_gate for this thread's (unit u, row r) ----
    float ig, cst = 0.f;
    {
        float a = b_i[u];
        for (int s = 0; s < NS; s++)
            a += xst[r * NS + s] * W_i[u * NS + s];
        ig = fsig(a);
    }
    __syncthreads();

    const int aoff  = n * SA;
    const int pbase = wv * 192 + lane;    // phase-B read base (gate 0)

    // ---- time loop: ONE barrier per step ----
    for (int t = 0; t < TS; t++) {
        const unsigned short* __restrict__ pA = Abuf[t & 1];
        unsigned short*       __restrict__ pB = Abuf[(t + 1) & 1];

        // Phase A: h-part preacts only (8 K-chunks); unroll 2 bounds A-frag
        // prefetch depth (full unroll let the compiler keep 8 frags live).
        f32x4 acc[NTILE];
        #pragma unroll
        for (int j = 0; j < NTILE; j++) acc[j] = (f32x4){0.f, 0.f, 0.f, 0.f};
        #pragma unroll 2
        for (int c = 0; c < 8; c++) {
            short8 a = *(const short8*)&pA[aoff + c * 32 + q * 8];
            #pragma unroll
            for (int j = 0; j < NTILE; j++)
                acc[j] = __builtin_amdgcn_mfma_f32_16x16x32_bf16(a, Bf[j][c], acc[j], 0, 0, 0);
        }
        if (q == 0) {   // lanes 0..15 hold rows 0..3 of col n -> wave-private pre region
            #pragma unroll
            for (int j = 0; j < NTILE; j++)
                *(f32x4*)&pre[wv * 192 + j * 64 + n * 4] = acc[j];
        }
        // intra-wave exchange: wave's own writes -> wave's own reads
        __asm__ volatile("s_waitcnt lgkmcnt(0)" ::: "memory");

        // Phase B: LSTM cell for (unit u, row r); x·Wx + bias folded in here
        {
            short8 xv = *(const short8*)&xcA[(unsigned)(t * 4 + r) * 8];
            short8 wf = *(const short8*)&WxL[(u)        * 8];
            short8 wg = *(const short8*)&WxL[(256 + u)  * 8];
            short8 wo = *(const short8*)&WxL[(512 + u)  * 8];
            float pf = pre[pbase]       + bf2f_s(wf[5]);
            float pg = pre[pbase + 64]  + bf2f_s(wg[5]);
            float po = pre[pbase + 128] + bf2f_s(wo[5]);
            #pragma unroll
            for (int d = 0; d < DDYN; d++) {
                float xd = bf2f_s(xv[d]);
                pf += xd * bf2f_s(wf[d]);
                pg += xd * bf2f_s(wg[d]);
                po += xd * bf2f_s(wo[d]);
            }
            float f  = fsig(pf);
            float g_ = ftanh(pg);
            float o  = fsig(po);
            cst = f * cst + ig * g_;
            float h = o * ftanh(cst);
            pB[r * SA + u] = f2bf(h);
        }
        __syncthreads();
    }

    // ---- head: out[b] = h . W_head + b_head (TS odd -> final h in buffer 1) ----
    {
        float h = bf2f(Abuf[1][r * SA + u]);
        pre[u * 4 + r] = h * W_head[u];
    }
    __syncthreads();
    if (tid < 64) {
        f32x4 s = *(const f32x4*)&pre[tid * 4];
        #pragma unroll
        for (int k = 1; k < 4; k++) {
            f32x4 v = *(const f32x4*)&pre[(tid + k * 64) * 4];
            #pragma unroll
            for (int rr = 0; rr < BS; rr++) s[rr] += v[rr];
        }
        #pragma unroll
        for (int off = 32; off > 0; off >>= 1)
            #pragma unroll
            for (int rr = 0; rr < BS; rr++) s[rr] += __shfl_down(s[rr], off, 64);
        if (tid == 0) {
            float bh = b_head[0];
            #pragma unroll
            for (int rr = 0; rr < BS; rr++) out[b0 + rr] = s[rr] + bh;
        }
    }
}

extern "C" void kernel_launch(void* const* d_in, const int* in_sizes, int n_in,
                              void* d_out, int out_size, void* d_ws, size_t ws_size,
                              hipStream_t stream) {
    ealstm_kernel<<<256, 1024, 0, stream>>>(
        (const float*)d_in[0],  (const float*)d_in[1],  (const float*)d_in[2],
        (const float*)d_in[3],  (const float*)d_in[4],  (const float*)d_in[5],
        (const float*)d_in[6],  (const float*)d_in[7],  (const float*)d_in[8],
        (const float*)d_in[9],  (const float*)d_in[10], (const float*)d_in[11],
        (float*)d_out);
}

// Round 7
// 639.795 us; speedup vs baseline: 7.7218x; 7.7218x over previous
//
#include <hip/hip_runtime.h>

#define HID  256
#define DDYN 5
#define NS   27
#define TS   365
#define BS   4            // batch rows per block
#define NW   16           // waves per block
#define UPW  16           // hidden units owned per wave
#define NTILE 3           // 16-col MFMA tiles per wave (one per gate)
#define SA   264          // Abuf row stride in bf16 elems (256 h + 8 pad)
#define G3   768          // 3 gates * 256

typedef short short8 __attribute__((ext_vector_type(8)));
typedef float f32x4  __attribute__((ext_vector_type(4)));

__device__ __forceinline__ unsigned short f2bf(float f) {
    union { float f; unsigned u; } v; v.f = f;
    unsigned r = v.u + 0x7FFFu + ((v.u >> 16) & 1u);   // RNE
    return (unsigned short)(r >> 16);
}
__device__ __forceinline__ float bf2f(unsigned short s) {
    union { unsigned u; float f; } v; v.u = ((unsigned)s) << 16;
    return v.f;
}
__device__ __forceinline__ float bf2f_s(short s) {
    union { unsigned u; float f; } v; v.u = ((unsigned)(unsigned short)s) << 16;
    return v.f;
}
__device__ __forceinline__ float fsig(float x) {
    float e = __builtin_amdgcn_exp2f(-1.4426950408889634f * x);
    return __builtin_amdgcn_rcpf(1.0f + e);
}
__device__ __forceinline__ float ftanh(float x) {
    float e = __builtin_amdgcn_exp2f(2.8853900817779268f * x);
    return 1.0f - 2.0f * __builtin_amdgcn_rcpf(1.0f + e);
}

// Register discipline (R2-R6 post-mortems), the three hard rules:
//  1. Bf MUST be statically indexed -> FULL unroll of the K-chunk loop.
//     (R6: "#pragma unroll 2" made Bf[j][c] runtime-indexed -> compiler
//      demoted all 96 weight regs to scratch -> 18 GB/dispatch re-fetch.)
//  2. No x/bias MFMA in the loop: it is a rank-6 update; its transient regs
//     (b8 frag + conditional A frag + exec juggling) were R5's 202 MB spill.
//     Folded into phase B as ~20 scalar FMAs from LDS (transient regs only).
//  3. Bound A-frag prefetch depth: memory clobber after each chunk stops the
//     scheduler from hoisting all 8 ds_reads (R4/R5: +28 live regs -> spill).
// Peak live ~122 of the 128 (V+A)/wave cap at 1024 threads.
__global__ __launch_bounds__(1024)
void ealstm_kernel(const float* __restrict__ x_dyn,  const float* __restrict__ x_stat,
                   const float* __restrict__ W_i,    const float* __restrict__ b_i,
                   const float* __restrict__ W_f,    const float* __restrict__ b_f,
                   const float* __restrict__ W_g,    const float* __restrict__ b_g,
                   const float* __restrict__ W_o,    const float* __restrict__ b_o,
                   const float* __restrict__ W_head, const float* __restrict__ b_head,
                   float* __restrict__ out)
{
    // LDS: 16896 + 12288 + 12288 + 23360 + 432 = 65264 B (<= 64 KiB)
    __shared__ __align__(16) unsigned short Abuf[2][16 * SA]; // h-only A tile, double-buffered
    __shared__ __align__(16) float          pre[NW * 192];    // h-part preacts, wave-private
    __shared__ __align__(16) unsigned short WxL[G3 * 8];      // per col: Wx[0..4], bias, 0, 0 (bf16)
    __shared__ __align__(16) unsigned short xcA[TS * 4 * 8];  // per (t,row): x[0..4], 1.0, 0, 0 (bf16)
    __shared__ __align__(16) float          xst[BS * NS];

    const int tid  = threadIdx.x;
    const int bid  = blockIdx.x;
    const int b0   = bid * BS;
    const int lane = tid & 63;
    const int wv   = tid >> 6;        // wave 0..15
    const int q    = lane >> 4;       // quad 0..3 (MFMA K-group)
    const int n    = lane & 15;       // MFMA col-in-tile
    const int up   = lane >> 2;       // unit-local 0..15 (phase B)
    const int r    = lane & 3;        // batch row 0..3 (phase B)
    const int u    = wv * UPW + up;   // owned hidden unit (phase B)

    // ---- init LDS ----
    for (int i = tid; i < 2 * 16 * SA / 2; i += 1024)
        ((unsigned int*)Abuf)[i] = 0u;                 // zero both A buffers (h0 = 0)
    for (int i = tid; i < BS * NS; i += 1024)
        xst[i] = x_stat[(b0 + i / NS) * NS + (i % NS)];
    for (int i = tid; i < TS * BS; i += 1024) {        // x rows, 16B-aligned per (t,row)
        int t = i >> 2, rr = i & 3;
        const float* xp = x_dyn + ((size_t)(b0 + rr) * TS + t) * DDYN;
        unsigned short* dst = &xcA[(unsigned)i * 8];
        #pragma unroll
        for (int d = 0; d < DDYN; d++) dst[d] = f2bf(xp[d]);
        dst[5] = 0x3F80; dst[6] = 0; dst[7] = 0;
    }
    if (tid < G3) {
        int col = tid;
        int gate = col >> 8, hc = col & 255;
        const float* Wg = gate == 0 ? W_f : (gate == 1 ? W_g : W_o);
        const float* bg = gate == 0 ? b_f : (gate == 1 ? b_g : b_o);
        #pragma unroll
        for (int d = 0; d < DDYN; d++) WxL[col * 8 + d] = f2bf(Wg[hc * (DDYN + HID) + d]);
        WxL[col * 8 + 5] = f2bf(bg[hc]);
        WxL[col * 8 + 6] = 0; WxL[col * 8 + 7] = 0;
    }

    // ---- persistent B fragments: 3 tiles x 8 K-chunks x 4 VGPR = 96 regs ----
    short8 Bf[NTILE][8];
    #pragma unroll
    for (int j = 0; j < NTILE; j++) {
        int urow = wv * UPW + n;           // weight row (hidden unit), gate j
        const float* Wg = j == 0 ? W_f : (j == 1 ? W_g : W_o);
        const float* wrow = Wg + urow * (DDYN + HID) + DDYN;   // skip x-part
        #pragma unroll
        for (int c = 0; c < 8; c++) {
            int k0 = c * 32 + q * 8;
            short8 fr;
            #pragma unroll
            for (int e = 0; e < 8; e++) fr[e] = (short)f2bf(wrow[k0 + e]);
            Bf[j][c] = fr;
        }
    }
    __syncthreads();

    // ---- i_gate for this thread's (unit u, row r) ----
    float ig, cst = 0.f;
    {
        float a = b_i[u];
        for (int s = 0; s < NS; s++)
            a += xst[r * NS + s] * W_i[u * NS + s];
        ig = fsig(a);
    }
    __syncthreads();

    const int aoff  = n * SA;
    const int pbase = wv * 192 + lane;    // phase-B read base (gate 0)

    // ---- time loop: ONE barrier per step ----
    for (int t = 0; t < TS; t++) {
        const unsigned short* __restrict__ pA = Abuf[t & 1];
        unsigned short*       __restrict__ pB = Abuf[(t + 1) & 1];

        // Phase A: h-part preacts (8 K-chunks, FULLY unrolled -> Bf static).
        f32x4 acc[NTILE];
        #pragma unroll
        for (int j = 0; j < NTILE; j++) acc[j] = (f32x4){0.f, 0.f, 0.f, 0.f};
        #pragma unroll
        for (int c = 0; c < 8; c++) {
            short8 a = *(const short8*)&pA[aoff + c * 32 + q * 8];
            #pragma unroll
            for (int j = 0; j < NTILE; j++)
                acc[j] = __builtin_amdgcn_mfma_f32_16x16x32_bf16(a, Bf[j][c], acc[j], 0, 0, 0);
            // clobber: next chunk's ds_read may not hoist above this point ->
            // at most ~2 A-frags live instead of 8 (R4/R5 spill source).
            __asm__ volatile("" ::: "memory");
        }
        if (q == 0) {   // lanes 0..15 hold rows 0..3 of col n -> wave-private pre region
            #pragma unroll
            for (int j = 0; j < NTILE; j++)
                *(f32x4*)&pre[wv * 192 + j * 64 + n * 4] = acc[j];
        }
        // intra-wave exchange: wave's own writes -> wave's own reads
        __asm__ volatile("s_waitcnt lgkmcnt(0)" ::: "memory");

        // Phase B: LSTM cell for (unit u, row r); x·Wx + bias folded in here
        {
            short8 xv = *(const short8*)&xcA[(unsigned)(t * 4 + r) * 8];
            short8 wf = *(const short8*)&WxL[(u)        * 8];
            short8 wg = *(const short8*)&WxL[(256 + u)  * 8];
            short8 wo = *(const short8*)&WxL[(512 + u)  * 8];
            float pf = pre[pbase]       + bf2f_s(wf[5]);
            float pg = pre[pbase + 64]  + bf2f_s(wg[5]);
            float po = pre[pbase + 128] + bf2f_s(wo[5]);
            #pragma unroll
            for (int d = 0; d < DDYN; d++) {
                float xd = bf2f_s(xv[d]);
                pf += xd * bf2f_s(wf[d]);
                pg += xd * bf2f_s(wg[d]);
                po += xd * bf2f_s(wo[d]);
            }
            float f  = fsig(pf);
            float g_ = ftanh(pg);
            float o  = fsig(po);
            cst = f * cst + ig * g_;
            float h = o * ftanh(cst);
            pB[r * SA + u] = f2bf(h);
        }
        __syncthreads();
    }

    // ---- head: out[b] = h . W_head + b_head (TS odd -> final h in buffer 1) ----
    {
        float h = bf2f(Abuf[1][r * SA + u]);
        pre[u * 4 + r] = h * W_head[u];
    }
    __syncthreads();
    if (tid < 64) {
        f32x4 s = *(const f32x4*)&pre[tid * 4];
        #pragma unroll
        for (int k = 1; k < 4; k++) {
            f32x4 v = *(const f32x4*)&pre[(tid + k * 64) * 4];
            #pragma unroll
            for (int rr = 0; rr < BS; rr++) s[rr] += v[rr];
        }
        #pragma unroll
        for (int off = 32; off > 0; off >>= 1)
            #pragma unroll
            for (int rr = 0; rr < BS; rr++) s[rr] += __shfl_down(s[rr], off, 64);
        if (tid == 0) {
            float bh = b_head[0];
            #pragma unroll
            for (int rr = 0; rr < BS; rr++) out[b0 + rr] = s[rr] + bh;
        }
    }
}

extern "C" void kernel_launch(void* const* d_in, const int* in_sizes, int n_in,
                              void* d_out, int out_size, void* d_ws, size_t ws_size,
                              hipStream_t stream) {
    ealstm_kernel<<<256, 1024, 0, stream>>>(
        (const float*)d_in[0],  (const float*)d_in[1],  (const float*)d_in[2],
        (const float*)d_in[3],  (const float*)d_in[4],  (const float*)d_in[5],
        (const float*)d_in[6],  (const float*)d_in[7],  (const float*)d_in[8],
        (const float*)d_in[9],  (const float*)d_in[10], (const float*)d_in[11],
        (float*)d_out);
}